// Round 8
// baseline (1312.585 us; speedup 1.0000x reference)
//
#include <hip/hip_runtime.h>

// ConvLSTM fp32, round 8: conv_kernel = r6 revert (147us known). The whole
// recurrence (7 steps of conv_rec+gates per layer) is now ONE persistent
// kernel per layer: 256 blocks (1/CU, co-resident), weights in LDS across
// steps, cx in registers, device-scope atomic grid barriers between phases.

#define WSTRIDE 442368   // per-layer conv weight elements: 27*64*256

__device__ __forceinline__ float wred_sum(float v) {
    #pragma unroll
    for (int o = 32; o > 0; o >>= 1) v += __shfl_down(v, o, 64);
    return __shfl(v, 0, 64);
}
__device__ __forceinline__ float fsig(float x)  { return 1.f / (1.f + __expf(-x)); }
__device__ __forceinline__ float ftanh(float x) { return 1.f - 2.f / (__expf(2.f*x) + 1.f); }

// h[nc][s][vox][ch] = emb[tok][ch]
__global__ __launch_bounds__(256) void embed_kernel(
    const int* __restrict__ code, const int* __restrict__ ncode,
    const float* __restrict__ emb, float* __restrict__ h)
{
    int e = blockIdx.x * 256 + threadIdx.x;   // < 2*7*512*64 = 458752
    int ch = e & 63;
    int pos = e >> 6;            // nc*7*512 + s*512 + vox
    int vox = pos & 511;
    int t = pos >> 9;            // nc*7 + s
    int s = t % 7, nc = t / 7;
    int tok = (s < 5) ? code[(nc*5 + s)*512 + vox]
                      : ncode[(nc*3 + (s-5))*512 + vox];
    h[e] = emb[tok*64 + ch];
}

// 3x3x3 SAME conv, Cin=64 -> Cout=256 (r6 version, 147us known-good).
// grid = 14 slab * 8 u * 4 cg = 448; block = u-plane (64 vox) x 64 co.
__global__ __launch_bounds__(256) void conv_kernel(
    const float* __restrict__ x, const float* __restrict__ wt,
    const float* __restrict__ bias, float* __restrict__ y)
{
    __shared__ float xs[2][16][10][14];   // halo'd: row r -> v=r-1, idx -> w=idx-1
    const int b = blockIdx.x;
    const int cg   = b & 3;
    const int u    = (b >> 2) & 7;
    const int slab = b >> 5;
    const int t = threadIdx.x;

    const int coq = t & 15, vg = t >> 4;
    const int co = cg*64 + coq*4;
    const int v0 = (vg >> 2) * 2;         // 0,2,4,6
    const int w0 = (vg & 3) * 2;          // 0,2,4,6

    const float* xbase = x + (size_t)(slab*512)*64;

    float4 sreg[2];
    auto stage_load = [&](int c) {
        const int du = c >> 2, cb = c & 3;
        const int uu = u + du - 1;
        #pragma unroll
        for (int p = 0; p < 2; ++p) {
            int s = p*256 + t;
            float4 v = {0.f, 0.f, 0.f, 0.f};
            if (s < 480) {
                int r = s / 48, rem = s % 48;
                int idx = rem >> 2, ci4 = rem & 3;
                if (uu >= 0 && uu < 8 && r >= 1 && r <= 8 && idx >= 1 && idx <= 8)
                    v = *(const float4*)(xbase +
                        (size_t)(uu*64 + (r-1)*8 + (idx-1))*64 + cb*16 + ci4*4);
            }
            sreg[p] = v;
        }
    };
    auto stage_store = [&](int buf) {
        #pragma unroll
        for (int p = 0; p < 2; ++p) {
            int s = p*256 + t;
            if (s < 480) {
                int r = s / 48, rem = s % 48;
                int idx = rem >> 2, ci4 = rem & 3;
                xs[buf][ci4*4+0][r][idx] = sreg[p].x;
                xs[buf][ci4*4+1][r][idx] = sreg[p].y;
                xs[buf][ci4*4+2][r][idx] = sreg[p].z;
                xs[buf][ci4*4+3][r][idx] = sreg[p].w;
            }
        }
    };

    float4 wv[2][9];
    auto wload = [&](int k, int wb) {
        int du = k >> 6;
        int gci = ((k >> 4) & 3)*16 + (k & 15);
        const float* wp = wt + ((size_t)(du*9)*64 + gci)*256 + co;
        #pragma unroll
        for (int tap = 0; tap < 9; ++tap)
            wv[wb][tap] = *(const float4*)(wp + (size_t)tap*16384);
    };

    stage_load(0);
    stage_store(0);
    wload(0, 0);
    __syncthreads();

    float acc[4][4] = {};
    for (int c = 0; c < 12; ++c) {
        const int buf = c & 1;
        if (c < 11) stage_load(c + 1);
        #pragma unroll 2
        for (int cl = 0; cl < 16; ++cl) {
            const int k = c*16 + cl;
            if (k < 191) wload(k + 1, (k + 1) & 1);
            float xpv[4][4];
            #pragma unroll
            for (int a = 0; a < 4; ++a) {
                const float2* xr = (const float2*)&xs[buf][cl][v0 + a][w0];
                float2 lo = xr[0], hi = xr[1];
                xpv[a][0] = lo.x; xpv[a][1] = lo.y;
                xpv[a][2] = hi.x; xpv[a][3] = hi.y;
            }
            const float4* wc = wv[k & 1];
            #pragma unroll
            for (int dv = 0; dv < 3; ++dv)
                #pragma unroll
                for (int dw = 0; dw < 3; ++dw) {
                    const float4 wq = wc[dv*3 + dw];
                    #pragma unroll
                    for (int j = 0; j < 4; ++j) {
                        float xv = xpv[(j>>1) + dv][(j&1) + dw];
                        acc[0][j] = fmaf(wq.x, xv, acc[0][j]);
                        acc[1][j] = fmaf(wq.y, xv, acc[1][j]);
                        acc[2][j] = fmaf(wq.z, xv, acc[2][j]);
                        acc[3][j] = fmaf(wq.w, xv, acc[3][j]);
                    }
                }
        }
        if (c < 11) stage_store((c + 1) & 1);
        __syncthreads();
    }

    const float4 bv = *(const float4*)(bias + co);
    #pragma unroll
    for (int j = 0; j < 4; ++j) {
        int vox = (v0 + (j>>1))*8 + w0 + (j&1);
        float4 o;
        o.x = acc[0][j] + bv.x; o.y = acc[1][j] + bv.y;
        o.z = acc[2][j] + bv.z; o.w = acc[3][j] + bv.w;
        *(float4*)(y + (size_t)((slab*512 + u*64 + vox)*256 + co)) = o;
    }
}

// Persistent per-layer recurrence: grid MUST be 256 (1 block/CU, co-resident).
// Per step: gates (fused, cx in regs) -> barrier -> conv(h[.,k]) -> barrier.
// Weights live in LDS for all 7 steps. 12 grid barriers per launch.
__global__ __launch_bounds__(256) void recur_kernel(
    float* __restrict__ h,              // [2][7][512][64] (rw)
    const float* __restrict__ gi,       // [2][7][512][256]
    const float* __restrict__ wt,       // wh layer slice [27][64][256]
    const float* __restrict__ bh,       // [256]
    const float* __restrict__ gg, const float* __restrict__ gb,
    float* __restrict__ ghat,           // [2][512][256]
    int* __restrict__ cnt)
{
    __shared__ __align__(16) float wlds[27648];   // [(du*9+tap)*64+ci][16co] 110.6KB
    __shared__ float xs[3][64][64];               // 49.2KB; reused as red[4096]
    const int b = blockIdx.x;
    const int t = threadIdx.x;
    const int cg   = b & 15;
    const int u    = (b >> 4) & 7;
    const int slab = b >> 7;

    // ---- stage weights once (persist across all 7 steps) ----
    #pragma unroll 4
    for (int i = 0; i < 27; ++i) {
        int j = i*256 + t;              // float4 id, 0..6911
        int du = j / 2304, r = j % 2304;
        int tap = r >> 8, rr = r & 255;
        int ci = rr >> 2, co4 = rr & 3;
        float4 v = *(const float4*)(wt +
            ((size_t)((du*9 + tap)*64 + ci))*256 + cg*16 + co4*4);
        *(float4*)&wlds[((du*9 + tap)*64 + ci)*16 + co4*4] = v;
    }

    // gates mapping: block owns 4 fixed rows
    const int lane = t & 63;
    const int grow = b*4 + (t >> 6);    // nc*512 + vox
    const int gnc = grow >> 9, gvox = grow & 511;
    float cx = 0.f;

    // conv mapping
    const int kp = t >> 6;              // ci quarter
    const int coq = lane & 3, vg = lane >> 2;
    const int co = cg*16 + coq*4;
    const int v0 = (vg >> 2) << 1, w0 = (vg & 3) << 1;
    int xoff[16];
    #pragma unroll
    for (int a = 0; a < 4; ++a)
        #pragma unroll
        for (int bb = 0; bb < 4; ++bb) {
            int vv = v0 - 1 + a, ww = w0 - 1 + bb;
            xoff[a*4+bb] = (vv >= 0 && vv < 8 && ww >= 0 && ww < 8) ? vv*8 + ww : -1;
        }
    const float4 bv = *(const float4*)(bh + co);

    int target = 0;
    auto grid_barrier = [&]() {
        __syncthreads();                 // all block threads' stores issued
        target += 256;
        if (t == 0) {
            __threadfence();             // device-scope release (L2 writeback)
            __hip_atomic_fetch_add(cnt, 1, __ATOMIC_ACQ_REL, __HIP_MEMORY_SCOPE_AGENT);
            while (__hip_atomic_load(cnt, __ATOMIC_ACQUIRE, __HIP_MEMORY_SCOPE_AGENT) < target) {}
            __threadfence();             // acquire side (invalidate stale L2/L1)
        }
        __syncthreads();
    };

    for (int k = 0; k < 7; ++k) {
        // ---------- gates phase (wave per row) ----------
        const float* gr = (k == 0) ? bh : ghat + (size_t)grow*256;
        float xi = gr[lane], xf = gr[64+lane], xc = gr[128+lane], xo = gr[192+lane];
        float mu = wred_sum(xi + xf + xc + xo) * (1.f/256.f);
        float di = xi-mu, df = xf-mu, dc = xc-mu, dq = xo-mu;
        float var = wred_sum(di*di + df*df + dc*dc + dq*dq) * (1.f/256.f);
        float rs = rsqrtf(var + 1e-5f);
        const float* gir = gi + ((size_t)(gnc*7 + k)*512 + gvox)*256;
        float Ig = gir[lane]     + di*rs*gg[lane]     + gb[lane];
        float Fg = gir[64+lane]  + df*rs*gg[64+lane]  + gb[64+lane];
        float Cg = gir[128+lane] + dc*rs*gg[128+lane] + gb[128+lane];
        float Og = gir[192+lane] + dq*rs*gg[192+lane] + gb[192+lane];
        cx = fsig(Fg) * cx + fsig(Ig) * ftanh(Cg);
        float hnew = fsig(Og) * ftanh(cx);
        h[((size_t)(gnc*7 + k)*512 + gvox)*64 + lane] = hnew;

        grid_barrier();                 // h[.,k] visible to all
        if (k == 6) break;

        // ---------- stage xs[3][64ci][64vox] from h[., k] ----------
        const float* hb = h + ((size_t)(slab*7 + k)*512)*64;
        #pragma unroll 4
        for (int i = 0; i < 12; ++i) {
            int j = i*256 + t;          // 0..3071 float4 id
            int du = j >> 10, r = j & 1023;
            int ci4 = r >> 6, vox = r & 63;
            int uu = u - 1 + du;
            float4 v = {0.f, 0.f, 0.f, 0.f};
            if (uu >= 0 && uu < 8)
                v = *(const float4*)(hb + (size_t)(uu*64 + vox)*64 + ci4*4);
            xs[du][ci4*4+0][vox] = v.x;
            xs[du][ci4*4+1][vox] = v.y;
            xs[du][ci4*4+2][vox] = v.z;
            xs[du][ci4*4+3][vox] = v.w;
        }
        __syncthreads();

        // ---------- conv phase (K-split 4-way over kp) ----------
        float acc[4][4] = {};
        #pragma unroll
        for (int du = 0; du < 3; ++du) {
            for (int cii = 0; cii < 16; ++cii) {
                const int ci = kp*16 + cii;
                float xpv[16];
                #pragma unroll
                for (int q = 0; q < 16; ++q)
                    xpv[q] = (xoff[q] >= 0) ? xs[du][ci][xoff[q]] : 0.f;
                const float* wp = &wlds[(du*9*64 + ci)*16 + coq*4];
                #pragma unroll
                for (int dv = 0; dv < 3; ++dv)
                    #pragma unroll
                    for (int dw = 0; dw < 3; ++dw) {
                        const float4 wq = *(const float4*)(wp + (dv*3 + dw)*1024);
                        #pragma unroll
                        for (int j = 0; j < 4; ++j) {
                            float xv = xpv[((j>>1) + dv)*4 + (j&1) + dw];
                            acc[0][j] = fmaf(wq.x, xv, acc[0][j]);
                            acc[1][j] = fmaf(wq.y, xv, acc[1][j]);
                            acc[2][j] = fmaf(wq.z, xv, acc[2][j]);
                            acc[3][j] = fmaf(wq.w, xv, acc[3][j]);
                        }
                    }
            }
        }
        __syncthreads();                // done reading xs -> reuse as red
        float* red = &xs[0][0][0];      // 16*256 = 4096 floats
        #pragma unroll
        for (int a = 0; a < 4; ++a)
            #pragma unroll
            for (int j = 0; j < 4; ++j)
                red[(a*4 + j)*256 + t] = acc[a][j];
        __syncthreads();
        if (t < 64) {                   // kp==0 lanes own the final sum
            float fin[16];
            #pragma unroll
            for (int i = 0; i < 16; ++i)
                fin[i] = red[i*256 + t] + red[i*256 + 64 + t]
                       + red[i*256 + 128 + t] + red[i*256 + 192 + t];
            #pragma unroll
            for (int j = 0; j < 4; ++j) {
                int vox = (v0 + (j>>1))*8 + w0 + (j&1);
                float4 o;
                o.x = fin[0*4+j] + bv.x; o.y = fin[1*4+j] + bv.y;
                o.z = fin[2*4+j] + bv.z; o.w = fin[3*4+j] + bv.w;
                *(float4*)(ghat + (size_t)((slab*512 + u*64 + vox)*256 + co)) = o;
            }
        }
        grid_barrier();                 // ghat visible for gates(k+1)
    }
}

// In-place LayerNorm over 256 channels, one wave per row (4 rows/block).
__global__ __launch_bounds__(256) void ln_kernel(
    float* __restrict__ yio, const float* __restrict__ g,
    const float* __restrict__ b)
{
    const int wid = threadIdx.x >> 6, lane = threadIdx.x & 63;
    const int row = blockIdx.x * 4 + wid;
    float4 v = *(const float4*)(yio + (size_t)row*256 + lane*4);
    float mu = wred_sum(v.x + v.y + v.z + v.w) * (1.f/256.f);
    float4 d = { v.x-mu, v.y-mu, v.z-mu, v.w-mu };
    float var = wred_sum(d.x*d.x + d.y*d.y + d.z*d.z + d.w*d.w) * (1.f/256.f);
    float rs = rsqrtf(var + 1e-5f);
    float4 gv = *(const float4*)(g + lane*4);
    float4 bv = *(const float4*)(b + lane*4);
    float4 o = { d.x*rs*gv.x + bv.x, d.y*rs*gv.y + bv.y,
                 d.z*rs*gv.z + bv.z, d.w*rs*gv.w + bv.w };
    *(float4*)(yio + (size_t)row*256 + lane*4) = o;
}

// Head: 4 voxels per block, one wave per voxel.
__global__ __launch_bounds__(256) void head_kernel(
    const float* __restrict__ h,      // [2][7][512][64]
    const float* __restrict__ w1, const float* __restrict__ b1,
    const float* __restrict__ lng, const float* __restrict__ lnb,
    const float* __restrict__ w2, const float* __restrict__ b2,
    const int* __restrict__ ncode,
    float* __restrict__ out)
{
    __shared__ float zv[4][64];
    __shared__ float lg[4][512];
    const int blk = blockIdx.x;               // 768 = 2n * 3sn * 128 voxgroups
    const int n = blk / 384;
    const int sn = (blk / 128) % 3;
    const int vox0 = (blk & 127) * 4;
    const int wid = threadIdx.x >> 6, lane = threadIdx.x & 63;
    const int vox = vox0 + wid;
    const int r = (n*3 + sn)*512 + vox;       // pred row
    const float* hv = h + (size_t)((n*7 + sn + 4)*512 + vox)*64;

    float yv = b1[lane];
    for (int kk = 0; kk < 64; ++kk) yv = fmaf(hv[kk], w1[kk*64 + lane], yv);
    float mu = wred_sum(yv) * (1.f/64.f);
    float d = yv - mu;
    float var = wred_sum(d*d) * (1.f/64.f);
    float ln = d * rsqrtf(var + 1e-5f) * lng[lane] + lnb[lane];
    zv[wid][lane] = 0.5f * ln * (1.f + erff(ln * 0.70710678118654752f));

    float l[8];
    #pragma unroll
    for (int j = 0; j < 8; ++j) l[j] = b2[j*64 + lane];
    for (int kk = 0; kk < 64; ++kk) {
        float zz = zv[wid][kk];
        #pragma unroll
        for (int j = 0; j < 8; ++j)
            l[j] = fmaf(zz, w2[kk*512 + j*64 + lane], l[j]);
    }
    #pragma unroll
    for (int j = 0; j < 8; ++j) lg[wid][j*64 + lane] = l[j];

    float m = l[0]; int mi = lane;
    #pragma unroll
    for (int j = 1; j < 8; ++j)
        if (l[j] > m) { m = l[j]; mi = j*64 + lane; }
    #pragma unroll
    for (int o = 32; o > 0; o >>= 1) {
        float om = __shfl_down(m, o, 64);
        int   oi = __shfl_down(mi, o, 64);
        if (om > m || (om == m && oi < mi)) { m = om; mi = oi; }
    }
    float maxv = __shfl(m, 0, 64);
    int   maxi = __shfl(mi, 0, 64);
    float es = 0.f;
    #pragma unroll
    for (int j = 0; j < 8; ++j) es += __expf(l[j] - maxv);
    float sum = wred_sum(es);
    if (lane == 0) {
        int target = ncode[(n*3 + sn)*512 + vox];
        float logp = lg[wid][target] - maxv - __logf(sum);
        atomicAdd(out + 1572864, -logp * (1.f/3072.f));
        out[1572865 + r] = (float)maxi;
    }

    __syncthreads();
    const int t = threadIdx.x;
    #pragma unroll
    for (int jj = 0; jj < 2; ++jj) {
        int co = t + jj*256;
        float4 o4 = { lg[0][co], lg[1][co], lg[2][co], lg[3][co] };
        *(float4*)(out + (size_t)((n*512 + co)*3 + sn)*512 + vox0) = o4;
    }
}

extern "C" void kernel_launch(void* const* d_in, const int* in_sizes, int n_in,
                              void* d_out, int out_size, void* d_ws, size_t ws_size,
                              hipStream_t stream) {
    (void)in_sizes; (void)n_in; (void)out_size; (void)ws_size;
    const int*   code  = (const int*)d_in[0];
    const int*   ncode = (const int*)d_in[1];
    const float* emb   = (const float*)d_in[2];
    const float* win   = (const float*)d_in[3];
    const float* bin_  = (const float*)d_in[4];
    const float* gin_w = (const float*)d_in[5];
    const float* gin_b = (const float*)d_in[6];
    const float* wh    = (const float*)d_in[7];
    const float* bh    = (const float*)d_in[8];
    const float* gh_w  = (const float*)d_in[9];
    const float* gh_b  = (const float*)d_in[10];
    const float* w1    = (const float*)d_in[11];
    const float* b1    = (const float*)d_in[12];
    const float* ln_g  = (const float*)d_in[13];
    const float* ln_b  = (const float*)d_in[14];
    const float* w2    = (const float*)d_in[15];
    const float* b2    = (const float*)d_in[16];
    float* out = (float*)d_out;

    float* h    = (float*)d_ws;        // [2][7][512][64]   = 458752
    float* gi   = h + 458752;          // [2][7][512][256]  = 1835008
    float* ghat = gi + 1835008;        // [2][512][256]     = 262144
    int*   cnt  = (int*)(ghat + 262144);  // 2 barrier counters

    hipMemsetAsync(out + 1572864, 0, sizeof(float), stream);   // loss accumulator
    hipMemsetAsync(cnt, 0, 2*sizeof(int), stream);             // barrier counters
    embed_kernel<<<1792, 256, 0, stream>>>(code, ncode, emb, h);

    for (int l = 0; l < 2; ++l) {
        conv_kernel<<<448, 256, 0, stream>>>(h, win + l*WSTRIDE, bin_ + l*256, gi);
        ln_kernel<<<1792, 256, 0, stream>>>(gi, gin_w + l*256, gin_b + l*256);
        recur_kernel<<<256, 256, 0, stream>>>(h, gi, wh + l*WSTRIDE, bh + l*256,
                                              gh_w + l*256, gh_b + l*256,
                                              ghat, cnt + l);
    }
    head_kernel<<<768, 256, 0, stream>>>(h, w1, b1, ln_g, ln_b, w2, b2, ncode, out);
}

// Round 9
// 1020.381 us; speedup vs baseline: 1.2864x; 1.2864x over previous
//
#include <hip/hip_runtime.h>

// ConvLSTM fp32, round 9: two-layer wavefront pipeline. Superstep s:
//   gates launch: gates1(s) + gates2(s-1)  (dual-LN fused, cx in-place)
//   conv  launch: up to 4 independent jobs {in1(s+1), rec1(s), in2(s), rec2(s)}
// Batched convs and ln_kernel are gone; conv job body = r6 conv_rec (proven).

#define WSTRIDE 442368   // per-layer conv weight elements: 27*64*256
#define XS      32768    // one k-slab of h: 512*64
#define HSTRIDE 229376   // nc stride of h: 7*512*64

__device__ __forceinline__ float wred_sum(float v) {
    #pragma unroll
    for (int o = 32; o > 0; o >>= 1) v += __shfl_down(v, o, 64);
    return __shfl(v, 0, 64);
}
__device__ __forceinline__ float fsig(float x)  { return 1.f / (1.f + __expf(-x)); }
__device__ __forceinline__ float ftanh(float x) { return 1.f - 2.f / (__expf(2.f*x) + 1.f); }

struct CJob { const float* x; const float* wt; const float* bias; float* y; };
struct GJob {
    const float* giraw; const float* ghat;
    const float* ginw; const float* ginb;
    const float* ghw;  const float* ghb;
    float* cx; float* h; int k; int k0;
};

// h[nc][s][vox][ch] = emb[tok][ch]
__global__ __launch_bounds__(256) void embed_kernel(
    const int* __restrict__ code, const int* __restrict__ ncode,
    const float* __restrict__ emb, float* __restrict__ h)
{
    int e = blockIdx.x * 256 + threadIdx.x;   // < 2*7*512*64 = 458752
    int ch = e & 63;
    int pos = e >> 6;            // nc*7*512 + s*512 + vox
    int vox = pos & 511;
    int t = pos >> 9;            // nc*7 + s
    int s = t % 7, nc = t / 7;
    int tok = (s < 5) ? code[(nc*5 + s)*512 + vox]
                      : ncode[(nc*3 + (s-5))*512 + vox];
    h[e] = emb[tok*64 + ch];
}

// One 3x3x3 SAME conv job (Cin=64 -> Cout=256) over 2 slabs; up to 4 jobs
// per launch via blockIdx.y. Body = r6 conv_rec (32vox x 16co per block,
// K-split 4-way + LDS reduce, wv[2][9] 1-deep weight prefetch).
__global__ __launch_bounds__(256) void conv_step_kernel(CJob j0, CJob j1, CJob j2, CJob j3)
{
    CJob J = j0;
    if (blockIdx.y == 1) J = j1;
    else if (blockIdx.y == 2) J = j2;
    else if (blockIdx.y == 3) J = j3;

    __shared__ float xs[2][16][6][14];    // rows r -> v = vh*4 + r - 1
    const int b = blockIdx.x;             // 512
    const int cg   = b & 15;
    const int vh   = (b >> 4) & 1;
    const int u    = (b >> 5) & 7;
    const int slab = b >> 8;
    const int t = threadIdx.x;

    const int kp = t >> 6;                // ci quarter
    const int lane = t & 63;
    const int coq = lane & 3, vg = lane >> 2;
    const int co = cg*16 + coq*4;
    const int pv = vg >> 2;               // local v row 0..3
    const int w0 = (vg & 3) * 2;          // 0,2,4,6

    const float* xbase = J.x + (size_t)slab * HSTRIDE;
    const float* wt = J.wt;

    float4 sreg[2];
    // chunk c: du = c>>2, cq = c&3; covers gci = kp4*16 + cq*4 + (0..3)
    auto stage_load = [&](int c) {
        const int du = c >> 2, cq = c & 3;
        const int uu = u + du - 1;
        #pragma unroll
        for (int p = 0; p < 2; ++p) {
            int s = p*256 + t;
            float4 v = {0.f, 0.f, 0.f, 0.f};
            if (s < 288) {
                int r = s / 48, rem = s % 48;
                int idx = rem >> 2, kp4 = rem & 3;
                int gv = vh*4 + r - 1;
                if (uu >= 0 && uu < 8 && gv >= 0 && gv < 8 && idx >= 1 && idx <= 8)
                    v = *(const float4*)(xbase +
                        (size_t)(uu*64 + gv*8 + (idx-1))*64 + kp4*16 + cq*4);
            }
            sreg[p] = v;
        }
    };
    auto stage_store = [&](int buf) {
        #pragma unroll
        for (int p = 0; p < 2; ++p) {
            int s = p*256 + t;
            if (s < 288) {
                int r = s / 48, rem = s % 48;
                int idx = rem >> 2, kp4 = rem & 3;
                xs[buf][kp4*4+0][r][idx] = sreg[p].x;
                xs[buf][kp4*4+1][r][idx] = sreg[p].y;
                xs[buf][kp4*4+2][r][idx] = sreg[p].z;
                xs[buf][kp4*4+3][r][idx] = sreg[p].w;
            }
        }
    };

    float4 wv[2][9];
    // n = 0..47: du = n>>4, gci = kp*16 + ((n>>2)&3)*4 + (n&3)
    auto wload = [&](int n, int wb) {
        int du = n >> 4;
        int gci = kp*16 + ((n >> 2) & 3)*4 + (n & 3);
        const float* wp = wt + ((size_t)(du*9)*64 + gci)*256 + co;
        #pragma unroll
        for (int tap = 0; tap < 9; ++tap)
            wv[wb][tap] = *(const float4*)(wp + (size_t)tap*16384);
    };

    stage_load(0);
    stage_store(0);
    wload(0, 0);
    __syncthreads();

    float acc[4][2] = {};
    for (int c = 0; c < 12; ++c) {
        const int buf = c & 1;
        if (c < 11) stage_load(c + 1);
        #pragma unroll 2
        for (int i = 0; i < 4; ++i) {
            const int n = c*4 + i;
            if (n < 47) wload(n + 1, (n + 1) & 1);
            const int cl = kp*4 + i;      // LDS slot
            float xpv[3][4];
            #pragma unroll
            for (int a = 0; a < 3; ++a) {
                const float2* xr = (const float2*)&xs[buf][cl][pv + a][w0];
                float2 lo = xr[0], hi = xr[1];
                xpv[a][0] = lo.x; xpv[a][1] = lo.y;
                xpv[a][2] = hi.x; xpv[a][3] = hi.y;
            }
            const float4* wc = wv[n & 1];
            #pragma unroll
            for (int dv = 0; dv < 3; ++dv)
                #pragma unroll
                for (int dw = 0; dw < 3; ++dw) {
                    const float4 wq = wc[dv*3 + dw];
                    #pragma unroll
                    for (int j = 0; j < 2; ++j) {
                        float xv = xpv[dv][j + dw];
                        acc[0][j] = fmaf(wq.x, xv, acc[0][j]);
                        acc[1][j] = fmaf(wq.y, xv, acc[1][j]);
                        acc[2][j] = fmaf(wq.z, xv, acc[2][j]);
                        acc[3][j] = fmaf(wq.w, xv, acc[3][j]);
                    }
                }
        }
        if (c < 11) stage_store((c + 1) & 1);
        __syncthreads();
    }

    // K-reduction: xs (2688 floats) reused as red[8][256]
    float* red = &xs[0][0][0][0];
    #pragma unroll
    for (int a = 0; a < 4; ++a)
        #pragma unroll
        for (int j = 0; j < 2; ++j)
            red[(a*2 + j)*256 + t] = acc[a][j];
    __syncthreads();
    if (t < 64) {                         // kp==0 threads own the final sum
        const float4 bv = *(const float4*)(J.bias + co);
        float fin[8];
        #pragma unroll
        for (int i = 0; i < 8; ++i)
            fin[i] = red[i*256 + t] + red[i*256 + 64 + t]
                   + red[i*256 + 128 + t] + red[i*256 + 192 + t];
        #pragma unroll
        for (int j = 0; j < 2; ++j) {
            int vox = u*64 + (vh*4 + pv)*8 + w0 + j;
            float4 o;
            o.x = fin[0*2 + j] + bv.x; o.y = fin[1*2 + j] + bv.y;
            o.z = fin[2*2 + j] + bv.z; o.w = fin[3*2 + j] + bv.w;
            *(float4*)(J.y + (size_t)((slab*512 + vox)*256 + co)) = o;
        }
    }
}

// Dual-LN LSTM cell: gates = LN_gin(gi_raw) + LN_gh(ghat or bh), then cx/h
// update. Up to 2 jobs (layer 1 step s, layer 2 step s-1) via blockIdx.y.
__global__ __launch_bounds__(256) void gates_step_kernel(GJob ja, GJob jb)
{
    const GJob J = (blockIdx.y == 0) ? ja : jb;
    const int wid = threadIdx.x >> 6, lane = threadIdx.x & 63;
    const int row = blockIdx.x * 4 + wid;     // nc*512 + vox, < 1024
    const int nc = row >> 9, vox = row & 511;

    const float* g1 = J.giraw + (size_t)row*256;
    float a0 = g1[lane], a1 = g1[64+lane], a2 = g1[128+lane], a3 = g1[192+lane];
    float mu1 = wred_sum(a0+a1+a2+a3) * (1.f/256.f);
    float d0=a0-mu1, d1=a1-mu1, d2=a2-mu1, d3=a3-mu1;
    float v1 = wred_sum(d0*d0+d1*d1+d2*d2+d3*d3) * (1.f/256.f);
    float rs1 = rsqrtf(v1 + 1e-5f);

    const float* g2 = J.k0 ? J.ghat : J.ghat + (size_t)row*256;
    float b0 = g2[lane], b1 = g2[64+lane], b2 = g2[128+lane], b3 = g2[192+lane];
    float mu2 = wred_sum(b0+b1+b2+b3) * (1.f/256.f);
    float e0=b0-mu2, e1=b1-mu2, e2=b2-mu2, e3=b3-mu2;
    float v2 = wred_sum(e0*e0+e1*e1+e2*e2+e3*e3) * (1.f/256.f);
    float rs2 = rsqrtf(v2 + 1e-5f);

    float Ig = d0*rs1*J.ginw[lane]     + J.ginb[lane]     + e0*rs2*J.ghw[lane]     + J.ghb[lane];
    float Fg = d1*rs1*J.ginw[64+lane]  + J.ginb[64+lane]  + e1*rs2*J.ghw[64+lane]  + J.ghb[64+lane];
    float Cg = d2*rs1*J.ginw[128+lane] + J.ginb[128+lane] + e2*rs2*J.ghw[128+lane] + J.ghb[128+lane];
    float Og = d3*rs1*J.ginw[192+lane] + J.ginb[192+lane] + e3*rs2*J.ghw[192+lane] + J.ghb[192+lane];

    float c_old = J.k0 ? 0.f : J.cx[(size_t)row*64 + lane];
    float c_new = fsig(Fg)*c_old + fsig(Ig)*ftanh(Cg);
    float h_new = fsig(Og)*ftanh(c_new);
    J.cx[(size_t)row*64 + lane] = c_new;
    J.h[((size_t)(nc*7 + J.k)*512 + vox)*64 + lane] = h_new;
}

// Head: 4 voxels per block, one wave per voxel (reads layer-2 h).
__global__ __launch_bounds__(256) void head_kernel(
    const float* __restrict__ h,      // [2][7][512][64]
    const float* __restrict__ w1, const float* __restrict__ b1,
    const float* __restrict__ lng, const float* __restrict__ lnb,
    const float* __restrict__ w2, const float* __restrict__ b2,
    const int* __restrict__ ncode,
    float* __restrict__ out)
{
    __shared__ float zv[4][64];
    __shared__ float lg[4][512];
    const int blk = blockIdx.x;               // 768 = 2n * 3sn * 128 voxgroups
    const int n = blk / 384;
    const int sn = (blk / 128) % 3;
    const int vox0 = (blk & 127) * 4;
    const int wid = threadIdx.x >> 6, lane = threadIdx.x & 63;
    const int vox = vox0 + wid;
    const int r = (n*3 + sn)*512 + vox;       // pred row
    const float* hv = h + (size_t)((n*7 + sn + 4)*512 + vox)*64;

    float yv = b1[lane];
    for (int kk = 0; kk < 64; ++kk) yv = fmaf(hv[kk], w1[kk*64 + lane], yv);
    float mu = wred_sum(yv) * (1.f/64.f);
    float d = yv - mu;
    float var = wred_sum(d*d) * (1.f/64.f);
    float ln = d * rsqrtf(var + 1e-5f) * lng[lane] + lnb[lane];
    zv[wid][lane] = 0.5f * ln * (1.f + erff(ln * 0.70710678118654752f));

    float l[8];
    #pragma unroll
    for (int j = 0; j < 8; ++j) l[j] = b2[j*64 + lane];
    for (int kk = 0; kk < 64; ++kk) {
        float zz = zv[wid][kk];
        #pragma unroll
        for (int j = 0; j < 8; ++j)
            l[j] = fmaf(zz, w2[kk*512 + j*64 + lane], l[j]);
    }
    #pragma unroll
    for (int j = 0; j < 8; ++j) lg[wid][j*64 + lane] = l[j];

    float m = l[0]; int mi = lane;
    #pragma unroll
    for (int j = 1; j < 8; ++j)
        if (l[j] > m) { m = l[j]; mi = j*64 + lane; }
    #pragma unroll
    for (int o = 32; o > 0; o >>= 1) {
        float om = __shfl_down(m, o, 64);
        int   oi = __shfl_down(mi, o, 64);
        if (om > m || (om == m && oi < mi)) { m = om; mi = oi; }
    }
    float maxv = __shfl(m, 0, 64);
    int   maxi = __shfl(mi, 0, 64);
    float es = 0.f;
    #pragma unroll
    for (int j = 0; j < 8; ++j) es += __expf(l[j] - maxv);
    float sum = wred_sum(es);
    if (lane == 0) {
        int target = ncode[(n*3 + sn)*512 + vox];
        float logp = lg[wid][target] - maxv - __logf(sum);
        atomicAdd(out + 1572864, -logp * (1.f/3072.f));
        out[1572865 + r] = (float)maxi;
    }

    __syncthreads();
    const int t = threadIdx.x;
    #pragma unroll
    for (int jj = 0; jj < 2; ++jj) {
        int co = t + jj*256;
        float4 o4 = { lg[0][co], lg[1][co], lg[2][co], lg[3][co] };
        *(float4*)(out + (size_t)((n*512 + co)*3 + sn)*512 + vox0) = o4;
    }
}

extern "C" void kernel_launch(void* const* d_in, const int* in_sizes, int n_in,
                              void* d_out, int out_size, void* d_ws, size_t ws_size,
                              hipStream_t stream) {
    (void)in_sizes; (void)n_in; (void)out_size; (void)ws_size;
    const int*   code  = (const int*)d_in[0];
    const int*   ncode = (const int*)d_in[1];
    const float* emb   = (const float*)d_in[2];
    const float* win   = (const float*)d_in[3];
    const float* bin_  = (const float*)d_in[4];
    const float* gin_w = (const float*)d_in[5];
    const float* gin_b = (const float*)d_in[6];
    const float* wh    = (const float*)d_in[7];
    const float* bh    = (const float*)d_in[8];
    const float* gh_w  = (const float*)d_in[9];
    const float* gh_b  = (const float*)d_in[10];
    const float* w1    = (const float*)d_in[11];
    const float* b1    = (const float*)d_in[12];
    const float* ln_g  = (const float*)d_in[13];
    const float* ln_b  = (const float*)d_in[14];
    const float* w2    = (const float*)d_in[15];
    const float* b2    = (const float*)d_in[16];
    float* out = (float*)d_out;

    float* h1     = (float*)d_ws;          // [2][7][512][64] (emb -> h1)
    float* h2     = h1 + 458752;           // [2][7][512][64]
    float* gi1raw = h2 + 458752;           // [2][512][256]
    float* gi2raw = gi1raw + 262144;       // [2][512][256]
    float* ghat1  = gi2raw + 262144;       // [2][512][256]
    float* ghat2  = ghat1 + 262144;        // [2][512][256]
    float* cx1    = ghat2 + 262144;        // [2][512][64]
    float* cx2    = cx1 + 65536;           // [2][512][64]

    hipMemsetAsync(out + 1572864, 0, sizeof(float), stream);   // loss accumulator
    embed_kernel<<<1792, 256, 0, stream>>>(code, ncode, emb, h1);

    // pre-loop: gi1raw(0) = conv(emb h1[0]) + bin1
    {
        CJob j = { h1 + 0*XS, win, bin_, gi1raw };
        conv_step_kernel<<<dim3(512, 1), 256, 0, stream>>>(j, j, j, j);
    }

    for (int s = 0; s <= 7; ++s) {
        // ---- gates launch: gates1(s) [s<=6], gates2(s-1) [s>=1] ----
        GJob g1 = { gi1raw, (s == 0) ? bh : ghat1,
                    gin_w, gin_b, gh_w, gh_b, cx1, h1, s, s == 0 };
        GJob g2 = { gi2raw, (s == 1) ? bh + 256 : ghat2,
                    gin_w + 256, gin_b + 256, gh_w + 256, gh_b + 256,
                    cx2, h2, s - 1, s == 1 };
        if (s == 0)
            gates_step_kernel<<<dim3(256, 1), 256, 0, stream>>>(g1, g1);
        else if (s <= 6)
            gates_step_kernel<<<dim3(256, 2), 256, 0, stream>>>(g1, g2);
        else
            gates_step_kernel<<<dim3(256, 1), 256, 0, stream>>>(g2, g2);

        // ---- conv launch: in1(s+1), rec1(s), in2(s), rec2(s) ----
        CJob jobs[4]; int nj = 0;
        if (s <= 5) jobs[nj++] = { h1 + (s+1)*XS, win, bin_, gi1raw };               // in1(s+1)
        if (s <= 5) jobs[nj++] = { h1 + s*XS, wh, bh, ghat1 };                        // rec1(s)
        if (s <= 6) jobs[nj++] = { h1 + s*XS, win + WSTRIDE, bin_ + 256, gi2raw };    // in2(s)
        if (s >= 1 && s <= 6)
                    jobs[nj++] = { h2 + (s-1)*XS, wh + WSTRIDE, bh + 256, ghat2 };    // rec2(s)
        if (nj > 0)
            conv_step_kernel<<<dim3(512, nj), 256, 0, stream>>>(
                jobs[0], jobs[nj > 1 ? 1 : 0], jobs[nj > 2 ? 2 : 0], jobs[nj > 3 ? 3 : 0]);
    }

    head_kernel<<<768, 256, 0, stream>>>(h2, w1, b1, ln_g, ln_b, w2, b2, ncode, out);
}

// Round 10
// 623.158 us; speedup vs baseline: 2.1063x; 1.6374x over previous
//
#include <hip/hip_runtime.h>

// ConvLSTM fp32, round 10: r9 wavefront schedule kept; conv job kernel
// rebuilt for FMA density: 4co x 4vox per thread (16 outputs), K-split-4,
// halo-padded zero-filled du-slab LDS (double-buffered), uniform weight
// addressing (wave-uniform base -> saddr loads), wv[2][9] 1-ahead prefetch.

#define WSTRIDE 442368   // per-layer conv weight elements: 27*64*256
#define XS      32768    // one k-slab of h: 512*64
#define HSTRIDE 229376   // nc stride of h: 7*512*64

__device__ __forceinline__ float wred_sum(float v) {
    #pragma unroll
    for (int o = 32; o > 0; o >>= 1) v += __shfl_down(v, o, 64);
    return __shfl(v, 0, 64);
}
__device__ __forceinline__ float fsig(float x)  { return 1.f / (1.f + __expf(-x)); }
__device__ __forceinline__ float ftanh(float x) { return 1.f - 2.f / (__expf(2.f*x) + 1.f); }

struct CJob { const float* x; const float* wt; const float* bias; float* y; };
struct GJob {
    const float* giraw; const float* ghat;
    const float* ginw; const float* ginb;
    const float* ghw;  const float* ghb;
    float* cx; float* h; int k; int k0;
};

// h[nc][s][vox][ch] = emb[tok][ch]
__global__ __launch_bounds__(256) void embed_kernel(
    const int* __restrict__ code, const int* __restrict__ ncode,
    const float* __restrict__ emb, float* __restrict__ h)
{
    int e = blockIdx.x * 256 + threadIdx.x;   // < 2*7*512*64 = 458752
    int ch = e & 63;
    int pos = e >> 6;            // nc*7*512 + s*512 + vox
    int vox = pos & 511;
    int t = pos >> 9;            // nc*7 + s
    int s = t % 7, nc = t / 7;
    int tok = (s < 5) ? code[(nc*5 + s)*512 + vox]
                      : ncode[(nc*3 + (s-5))*512 + vox];
    h[e] = emb[tok*64 + ch];
}

// One 3x3x3 SAME conv job (Cin=64 -> Cout=256) over 2 slabs; up to 4 jobs
// per launch via blockIdx.y. Block = full u-plane (64 vox) x 16 co,
// thread = 4co x 4vox (2x2 patch), K(ci) split 4-way + LDS reduce.
// grid.x per job = 2 slab * 8 u * 16 cg = 256.
__global__ __launch_bounds__(256) void conv_step_kernel(CJob j0, CJob j1, CJob j2, CJob j3)
{
    CJob J = j0;
    if (blockIdx.y == 1) J = j1;
    else if (blockIdx.y == 2) J = j2;
    else if (blockIdx.y == 3) J = j3;

    __shared__ float xs[2][64][10][14];   // halo-padded du-slab, dbuf: 71,680 B
    const int b = blockIdx.x;             // 256
    const int cg   = b & 15;
    const int u    = (b >> 4) & 7;
    const int slab = b >> 7;
    const int t = threadIdx.x;
    const int kp = t >> 6;                // ci quarter
    const int lane = t & 63;
    const int coq = lane & 3, vg = lane >> 2;
    const int co = cg*16 + coq*4;
    const int v0 = (vg >> 2) * 2;         // 0,2,4,6
    const int w0 = (vg & 3) * 2;          // 0,2,4,6

    // zero everything once: halo cells stay 0 for the whole kernel
    {
        float* p = &xs[0][0][0][0];
        for (int i = t; i < 2*64*140; i += 256) p[i] = 0.f;
    }

    const float* xbase = J.x + (size_t)slab * HSTRIDE;

    float4 sreg[4];
    auto stage_load = [&](int du) {       // slab uu = u + du - 1 -> registers
        const int uu = u + du - 1;
        const bool ok = (uu >= 0) && (uu < 8);
        const float4* p4 = (const float4*)(xbase + (size_t)uu*64*64);
        #pragma unroll
        for (int p = 0; p < 4; ++p) {
            float4 v = {0.f, 0.f, 0.f, 0.f};
            if (ok) v = p4[p*256 + t];
            sreg[p] = v;
        }
    };
    auto stage_store = [&](int buf) {     // scatter to interior of padded tile
        #pragma unroll
        for (int p = 0; p < 4; ++p) {
            int q = p*256 + t;            // q = vox*16 + ci4
            int vox = q >> 4, ci0 = (q & 15) * 4;
            int r = (vox >> 3) + 1, wdx = (vox & 7) + 1;
            xs[buf][ci0+0][r][wdx] = sreg[p].x;
            xs[buf][ci0+1][r][wdx] = sreg[p].y;
            xs[buf][ci0+2][r][wdx] = sreg[p].z;
            xs[buf][ci0+3][r][wdx] = sreg[p].w;
        }
    };

    float4 wv[2][9];
    // weight base is wave-uniform; only coq*16B varies per lane
    auto wload = [&](int du, int ci, int wb) {
        const float* wp = J.wt + (((size_t)(du*576 + ci)) << 8) + cg*16 + coq*4;
        #pragma unroll
        for (int tap = 0; tap < 9; ++tap)
            wv[wb][tap] = *(const float4*)(wp + tap*16384);
    };

    __syncthreads();                      // zero-init complete
    stage_load(0);
    stage_store(0);
    wload(0, kp*16, 0);
    __syncthreads();                      // chunk 0 staged

    float acc[4][4] = {};
    for (int du = 0; du < 3; ++du) {
        const int buf = du & 1;
        if (du < 2) stage_load(du + 1);   // long-latency, lands before store
        #pragma unroll 2
        for (int i = 0; i < 16; ++i) {
            const int kidx = du*16 + i;
            if (kidx < 47)                // 1-ahead weight prefetch
                wload((kidx + 1) >> 4, kp*16 + ((kidx + 1) & 15), (kidx + 1) & 1);
            const int ci = kp*16 + i;
            float xpv[4][4];
            #pragma unroll
            for (int a = 0; a < 4; ++a) {
                const float2* xr = (const float2*)&xs[buf][ci][v0 + a][w0];
                float2 lo = xr[0], hi = xr[1];
                xpv[a][0] = lo.x; xpv[a][1] = lo.y;
                xpv[a][2] = hi.x; xpv[a][3] = hi.y;
            }
            const float4* wc = wv[kidx & 1];
            #pragma unroll
            for (int dv = 0; dv < 3; ++dv)
                #pragma unroll
                for (int dw = 0; dw < 3; ++dw) {
                    const float4 wq = wc[dv*3 + dw];
                    #pragma unroll
                    for (int j = 0; j < 4; ++j) {
                        float xv = xpv[(j>>1) + dv][(j&1) + dw];
                        acc[0][j] = fmaf(wq.x, xv, acc[0][j]);
                        acc[1][j] = fmaf(wq.y, xv, acc[1][j]);
                        acc[2][j] = fmaf(wq.z, xv, acc[2][j]);
                        acc[3][j] = fmaf(wq.w, xv, acc[3][j]);
                    }
                }
        }
        if (du < 2) stage_store((du + 1) & 1);
        __syncthreads();
    }

    // K-reduction across the 4 kp classes: reuse xs as red[16][256]
    float* red = &xs[0][0][0][0];
    #pragma unroll
    for (int a = 0; a < 4; ++a)
        #pragma unroll
        for (int j = 0; j < 4; ++j)
            red[(a*4 + j)*256 + t] = acc[a][j];
    __syncthreads();
    if (t < 64) {                         // kp==0 class: same (coq,vg) mapping
        const float4 bv = *(const float4*)(J.bias + co);
        float fin[16];
        #pragma unroll
        for (int i = 0; i < 16; ++i)
            fin[i] = red[i*256 + t] + red[i*256 + 64 + t]
                   + red[i*256 + 128 + t] + red[i*256 + 192 + t];
        #pragma unroll
        for (int j = 0; j < 4; ++j) {
            int vox = (v0 + (j>>1))*8 + w0 + (j&1);
            float4 o;
            o.x = fin[0*4+j] + bv.x; o.y = fin[1*4+j] + bv.y;
            o.z = fin[2*4+j] + bv.z; o.w = fin[3*4+j] + bv.w;
            *(float4*)(J.y + (size_t)((slab*512 + u*64 + vox)*256 + co)) = o;
        }
    }
}

// Dual-LN LSTM cell: gates = LN_gin(gi_raw) + LN_gh(ghat or bh), then cx/h
// update. Up to 2 jobs (layer 1 step s, layer 2 step s-1) via blockIdx.y.
__global__ __launch_bounds__(256) void gates_step_kernel(GJob ja, GJob jb)
{
    const GJob J = (blockIdx.y == 0) ? ja : jb;
    const int wid = threadIdx.x >> 6, lane = threadIdx.x & 63;
    const int row = blockIdx.x * 4 + wid;     // nc*512 + vox, < 1024
    const int nc = row >> 9, vox = row & 511;

    const float* g1 = J.giraw + (size_t)row*256;
    float a0 = g1[lane], a1 = g1[64+lane], a2 = g1[128+lane], a3 = g1[192+lane];
    float mu1 = wred_sum(a0+a1+a2+a3) * (1.f/256.f);
    float d0=a0-mu1, d1=a1-mu1, d2=a2-mu1, d3=a3-mu1;
    float v1 = wred_sum(d0*d0+d1*d1+d2*d2+d3*d3) * (1.f/256.f);
    float rs1 = rsqrtf(v1 + 1e-5f);

    const float* g2 = J.k0 ? J.ghat : J.ghat + (size_t)row*256;
    float b0 = g2[lane], b1 = g2[64+lane], b2 = g2[128+lane], b3 = g2[192+lane];
    float mu2 = wred_sum(b0+b1+b2+b3) * (1.f/256.f);
    float e0=b0-mu2, e1=b1-mu2, e2=b2-mu2, e3=b3-mu2;
    float v2 = wred_sum(e0*e0+e1*e1+e2*e2+e3*e3) * (1.f/256.f);
    float rs2 = rsqrtf(v2 + 1e-5f);

    float Ig = d0*rs1*J.ginw[lane]     + J.ginb[lane]     + e0*rs2*J.ghw[lane]     + J.ghb[lane];
    float Fg = d1*rs1*J.ginw[64+lane]  + J.ginb[64+lane]  + e1*rs2*J.ghw[64+lane]  + J.ghb[64+lane];
    float Cg = d2*rs1*J.ginw[128+lane] + J.ginb[128+lane] + e2*rs2*J.ghw[128+lane] + J.ghb[128+lane];
    float Og = d3*rs1*J.ginw[192+lane] + J.ginb[192+lane] + e3*rs2*J.ghw[192+lane] + J.ghb[192+lane];

    float c_old = J.k0 ? 0.f : J.cx[(size_t)row*64 + lane];
    float c_new = fsig(Fg)*c_old + fsig(Ig)*ftanh(Cg);
    float h_new = fsig(Og)*ftanh(c_new);
    J.cx[(size_t)row*64 + lane] = c_new;
    J.h[((size_t)(nc*7 + J.k)*512 + vox)*64 + lane] = h_new;
}

// Head: 4 voxels per block, one wave per voxel (reads layer-2 h).
__global__ __launch_bounds__(256) void head_kernel(
    const float* __restrict__ h,      // [2][7][512][64]
    const float* __restrict__ w1, const float* __restrict__ b1,
    const float* __restrict__ lng, const float* __restrict__ lnb,
    const float* __restrict__ w2, const float* __restrict__ b2,
    const int* __restrict__ ncode,
    float* __restrict__ out)
{
    __shared__ float zv[4][64];
    __shared__ float lg[4][512];
    const int blk = blockIdx.x;               // 768 = 2n * 3sn * 128 voxgroups
    const int n = blk / 384;
    const int sn = (blk / 128) % 3;
    const int vox0 = (blk & 127) * 4;
    const int wid = threadIdx.x >> 6, lane = threadIdx.x & 63;
    const int vox = vox0 + wid;
    const int r = (n*3 + sn)*512 + vox;       // pred row
    const float* hv = h + (size_t)((n*7 + sn + 4)*512 + vox)*64;

    float yv = b1[lane];
    for (int kk = 0; kk < 64; ++kk) yv = fmaf(hv[kk], w1[kk*64 + lane], yv);
    float mu = wred_sum(yv) * (1.f/64.f);
    float d = yv - mu;
    float var = wred_sum(d*d) * (1.f/64.f);
    float ln = d * rsqrtf(var + 1e-5f) * lng[lane] + lnb[lane];
    zv[wid][lane] = 0.5f * ln * (1.f + erff(ln * 0.70710678118654752f));

    float l[8];
    #pragma unroll
    for (int j = 0; j < 8; ++j) l[j] = b2[j*64 + lane];
    for (int kk = 0; kk < 64; ++kk) {
        float zz = zv[wid][kk];
        #pragma unroll
        for (int j = 0; j < 8; ++j)
            l[j] = fmaf(zz, w2[kk*512 + j*64 + lane], l[j]);
    }
    #pragma unroll
    for (int j = 0; j < 8; ++j) lg[wid][j*64 + lane] = l[j];

    float m = l[0]; int mi = lane;
    #pragma unroll
    for (int j = 1; j < 8; ++j)
        if (l[j] > m) { m = l[j]; mi = j*64 + lane; }
    #pragma unroll
    for (int o = 32; o > 0; o >>= 1) {
        float om = __shfl_down(m, o, 64);
        int   oi = __shfl_down(mi, o, 64);
        if (om > m || (om == m && oi < mi)) { m = om; mi = oi; }
    }
    float maxv = __shfl(m, 0, 64);
    int   maxi = __shfl(mi, 0, 64);
    float es = 0.f;
    #pragma unroll
    for (int j = 0; j < 8; ++j) es += __expf(l[j] - maxv);
    float sum = wred_sum(es);
    if (lane == 0) {
        int target = ncode[(n*3 + sn)*512 + vox];
        float logp = lg[wid][target] - maxv - __logf(sum);
        atomicAdd(out + 1572864, -logp * (1.f/3072.f));
        out[1572865 + r] = (float)maxi;
    }

    __syncthreads();
    const int t = threadIdx.x;
    #pragma unroll
    for (int jj = 0; jj < 2; ++jj) {
        int co = t + jj*256;
        float4 o4 = { lg[0][co], lg[1][co], lg[2][co], lg[3][co] };
        *(float4*)(out + (size_t)((n*512 + co)*3 + sn)*512 + vox0) = o4;
    }
}

extern "C" void kernel_launch(void* const* d_in, const int* in_sizes, int n_in,
                              void* d_out, int out_size, void* d_ws, size_t ws_size,
                              hipStream_t stream) {
    (void)in_sizes; (void)n_in; (void)out_size; (void)ws_size;
    const int*   code  = (const int*)d_in[0];
    const int*   ncode = (const int*)d_in[1];
    const float* emb   = (const float*)d_in[2];
    const float* win   = (const float*)d_in[3];
    const float* bin_  = (const float*)d_in[4];
    const float* gin_w = (const float*)d_in[5];
    const float* gin_b = (const float*)d_in[6];
    const float* wh    = (const float*)d_in[7];
    const float* bh    = (const float*)d_in[8];
    const float* gh_w  = (const float*)d_in[9];
    const float* gh_b  = (const float*)d_in[10];
    const float* w1    = (const float*)d_in[11];
    const float* b1    = (const float*)d_in[12];
    const float* ln_g  = (const float*)d_in[13];
    const float* ln_b  = (const float*)d_in[14];
    const float* w2    = (const float*)d_in[15];
    const float* b2    = (const float*)d_in[16];
    float* out = (float*)d_out;

    float* h1     = (float*)d_ws;          // [2][7][512][64] (emb -> h1)
    float* h2     = h1 + 458752;           // [2][7][512][64]
    float* gi1raw = h2 + 458752;           // [2][512][256]
    float* gi2raw = gi1raw + 262144;       // [2][512][256]
    float* ghat1  = gi2raw + 262144;       // [2][512][256]
    float* ghat2  = ghat1 + 262144;        // [2][512][256]
    float* cx1    = ghat2 + 262144;        // [2][512][64]
    float* cx2    = cx1 + 65536;           // [2][512][64]

    hipMemsetAsync(out + 1572864, 0, sizeof(float), stream);   // loss accumulator
    embed_kernel<<<1792, 256, 0, stream>>>(code, ncode, emb, h1);

    // pre-loop: gi1raw(0) = conv(emb h1[0]) + bin1
    {
        CJob j = { h1 + 0*XS, win, bin_, gi1raw };
        conv_step_kernel<<<dim3(256, 1), 256, 0, stream>>>(j, j, j, j);
    }

    for (int s = 0; s <= 7; ++s) {
        // ---- gates launch: gates1(s) [s<=6], gates2(s-1) [s>=1] ----
        GJob g1 = { gi1raw, (s == 0) ? bh : ghat1,
                    gin_w, gin_b, gh_w, gh_b, cx1, h1, s, s == 0 };
        GJob g2 = { gi2raw, (s == 1) ? bh + 256 : ghat2,
                    gin_w + 256, gin_b + 256, gh_w + 256, gh_b + 256,
                    cx2, h2, s - 1, s == 1 };
        if (s == 0)
            gates_step_kernel<<<dim3(256, 1), 256, 0, stream>>>(g1, g1);
        else if (s <= 6)
            gates_step_kernel<<<dim3(256, 2), 256, 0, stream>>>(g1, g2);
        else
            gates_step_kernel<<<dim3(256, 1), 256, 0, stream>>>(g2, g2);

        // ---- conv launch: in1(s+1), rec1(s), in2(s), rec2(s) ----
        CJob jobs[4]; int nj = 0;
        if (s <= 5) jobs[nj++] = { h1 + (s+1)*XS, win, bin_, gi1raw };               // in1(s+1)
        if (s <= 5) jobs[nj++] = { h1 + s*XS, wh, bh, ghat1 };                        // rec1(s)
        if (s <= 6) jobs[nj++] = { h1 + s*XS, win + WSTRIDE, bin_ + 256, gi2raw };    // in2(s)
        if (s >= 1 && s <= 6)
                    jobs[nj++] = { h2 + (s-1)*XS, wh + WSTRIDE, bh + 256, ghat2 };    // rec2(s)
        if (nj > 0)
            conv_step_kernel<<<dim3(256, nj), 256, 0, stream>>>(
                jobs[0], jobs[nj > 1 ? 1 : 0], jobs[nj > 2 ? 2 : 0], jobs[nj > 3 ? 3 : 0]);
    }

    head_kernel<<<768, 256, 0, stream>>>(h2, w1, b1, ln_g, ln_b, w2, b2, ncode, out);
}